// Round 4
// baseline (250.616 us; speedup 1.0000x reference)
//
#include <hip/hip_runtime.h>
#include <math.h>

// Hit-miss transform: out[i][j] = min_{di,dj}(x[i+di][j+dj] - Khit[di][dj])
//                               - max_{di,dj}(x[i+di][j+dj] - Kmiss[di][dj])
// H=W=4096 fp32 input, 5x5 kernels, output 4092x4092 fp32.
//
// R7: pixel-pair packed subtracts in PURE C. R6 proved the packing win is
// real (VALU busy 30->20us) but inline-asm pksub with "s"-pair operands
// destroyed the schedule (stall 11->34us: SGPR pairs not allocated, loads
// no longer hoisted). Re-cast: pack PIXEL pairs, not hit/miss pairs:
//   t_j = (v[p+j], v[p+j+1]) + (-w_j, -w_j)   -> one v_pk_add_f32 / 2 pixels
// from <2 x float> fadd (clang gfx90a+ packed-fp32 pattern; weights
// pre-negated so it's a plain fadd; x+(-w) is IEEE-identical to x-w).
// Overlapping pairs solved by dual-alignment row loads: A = e0..e7
// (2x dwordx4), B = e1..e6 (dwordx4 + dwordx2 at +4B, dword-aligned, same
// address reg + imm offsets). All pairs {A0,B0,A1,B1,A2,B2,A3} are natural
// even-aligned VGPR pairs -> zero shuffle movs. min/max associative ->
// bit-exact. Degrades to R4's scalar subs if pk codegen doesn't fire.
// Grid packing kept: 4 x 1023 = 4092 blocks = 2 exact resident rounds;
// __launch_bounds__(256,8) pins VGPR<=64 to keep 8 blocks/CU.

constexpr int KS  = 5;
constexpr int WW  = 4096;
constexpr int HO  = 4092;
constexpr int WO  = 4092;
constexpr int CG  = WO / 4;   // 1023 column groups
constexpr int RPT = 4;        // output rows per thread (4092 = 4*1023)

typedef float v2f  __attribute__((ext_vector_type(2)));
typedef float f4a4 __attribute__((ext_vector_type(4), aligned(4)));
typedef float f2a4 __attribute__((ext_vector_type(2), aligned(4)));
typedef float f4a16 __attribute__((ext_vector_type(4), aligned(16)));

__device__ __forceinline__ float min3f(float a, float b, float c) {
    float d;
    asm("v_min3_f32 %0, %1, %2, %3" : "=v"(d) : "v"(a), "v"(b), "v"(c));
    return d;
}
__device__ __forceinline__ float max3f(float a, float b, float c) {
    float d;
    asm("v_max3_f32 %0, %1, %2, %3" : "=v"(d) : "v"(a), "v"(b), "v"(c));
    return d;
}

// 5-leaf reductions; acc variants keep dependency depth 2 from acc.
__device__ __forceinline__ float red5_min(float t0, float t1, float t2, float t3, float t4) {
    return min3f(min3f(t0, t1, t2), t3, t4);
}
__device__ __forceinline__ float red5_max(float t0, float t1, float t2, float t3, float t4) {
    return max3f(max3f(t0, t1, t2), t3, t4);
}
__device__ __forceinline__ float red5acc_min(float acc, float t0, float t1, float t2, float t3, float t4) {
    return fminf(min3f(t0, t1, t2), min3f(t3, t4, acc));
}
__device__ __forceinline__ float red5acc_max(float acc, float t0, float t1, float t2, float t3, float t4) {
    return fmaxf(max3f(t0, t1, t2), max3f(t3, t4, acc));
}

__global__ __launch_bounds__(256, 8) void hitmiss_kernel(
    const float* __restrict__ x,
    const float* __restrict__ kh,
    const float* __restrict__ km,
    float* __restrict__ out)
{
    const int cg = blockIdx.x * blockDim.x + threadIdx.x;  // column group
    if (cg >= CG) return;
    const int j0 = cg * 4;
    const int r0 = blockIdx.y * RPT;

    // Pre-negated weights, uniform -> SGPRs. t = v + nw == v - w exactly.
    float nh[KS * KS], nm[KS * KS];
#pragma unroll
    for (int k = 0; k < KS * KS; ++k) {
        nh[k] = -kh[k];
        nm[k] = -km[k];
    }

    const float* base = x + (size_t)r0 * WW + j0;

    float mn[RPT][4], mx[RPT][4];

#pragma unroll
    for (int i = 0; i < RPT + 4; ++i) {
        const float* rp = base + (size_t)i * WW;
        // A: elements 0..7 (16B-aligned). B: elements 1..6 (+4B, dword-aligned;
        // same base register, immediate offsets fold into the loads).
        f4a16 a0 = *reinterpret_cast<const f4a16*>(rp);       // e0..e3
        f4a16 a1 = *reinterpret_cast<const f4a16*>(rp + 4);   // e4..e7
        f4a4  b0 = *reinterpret_cast<const f4a4 *>(rp + 1);   // e1..e4
        f2a4  b1 = *reinterpret_cast<const f2a4 *>(rp + 5);   // e5,e6

        const v2f A0 = {a0.x, a0.y}, A1 = {a0.z, a0.w};
        const v2f A2 = {a1.x, a1.y}, A3 = {a1.z, a1.w};
        const v2f B0 = {b0.x, b0.y}, B1 = {b0.z, b0.w};
        const v2f B2 = {b1.x, b1.y};

        // j-th sliding pair for pixel-pair (0,1) and (2,3).
        const v2f p01[KS] = {A0, B0, A1, B1, A2};
        const v2f p23[KS] = {A1, B1, A2, B2, A3};

#pragma unroll
        for (int o = 0; o < RPT; ++o) {
            const int di = i - o;              // static after unroll
            if (di < 0 || di > KS - 1) continue;
            const int kb = di * KS;

            v2f th01[KS], tm01[KS], th23[KS], tm23[KS];
#pragma unroll
            for (int j = 0; j < KS; ++j) {
                th01[j] = p01[j] + nh[kb + j];   // v_pk_add_f32, SGPR splat
                tm01[j] = p01[j] + nm[kb + j];
                th23[j] = p23[j] + nh[kb + j];
                tm23[j] = p23[j] + nm[kb + j];
            }

            if (di == 0) {
                mn[o][0] = red5_min(th01[0].x, th01[1].x, th01[2].x, th01[3].x, th01[4].x);
                mn[o][1] = red5_min(th01[0].y, th01[1].y, th01[2].y, th01[3].y, th01[4].y);
                mn[o][2] = red5_min(th23[0].x, th23[1].x, th23[2].x, th23[3].x, th23[4].x);
                mn[o][3] = red5_min(th23[0].y, th23[1].y, th23[2].y, th23[3].y, th23[4].y);
                mx[o][0] = red5_max(tm01[0].x, tm01[1].x, tm01[2].x, tm01[3].x, tm01[4].x);
                mx[o][1] = red5_max(tm01[0].y, tm01[1].y, tm01[2].y, tm01[3].y, tm01[4].y);
                mx[o][2] = red5_max(tm23[0].x, tm23[1].x, tm23[2].x, tm23[3].x, tm23[4].x);
                mx[o][3] = red5_max(tm23[0].y, tm23[1].y, tm23[2].y, tm23[3].y, tm23[4].y);
            } else {
                mn[o][0] = red5acc_min(mn[o][0], th01[0].x, th01[1].x, th01[2].x, th01[3].x, th01[4].x);
                mn[o][1] = red5acc_min(mn[o][1], th01[0].y, th01[1].y, th01[2].y, th01[3].y, th01[4].y);
                mn[o][2] = red5acc_min(mn[o][2], th23[0].x, th23[1].x, th23[2].x, th23[3].x, th23[4].x);
                mn[o][3] = red5acc_min(mn[o][3], th23[0].y, th23[1].y, th23[2].y, th23[3].y, th23[4].y);
                mx[o][0] = red5acc_max(mx[o][0], tm01[0].x, tm01[1].x, tm01[2].x, tm01[3].x, tm01[4].x);
                mx[o][1] = red5acc_max(mx[o][1], tm01[0].y, tm01[1].y, tm01[2].y, tm01[3].y, tm01[4].y);
                mx[o][2] = red5acc_max(mx[o][2], tm23[0].x, tm23[1].x, tm23[2].x, tm23[3].x, tm23[4].x);
                mx[o][3] = red5acc_max(mx[o][3], tm23[0].y, tm23[1].y, tm23[2].y, tm23[3].y, tm23[4].y);
            }
        }

        // Output row o = i-4 complete; store and free its accumulators.
        if (i >= KS - 1) {
            const int o = i - (KS - 1);
            float4 oo;
            oo.x = mn[o][0] - mx[o][0];
            oo.y = mn[o][1] - mx[o][1];
            oo.z = mn[o][2] - mx[o][2];
            oo.w = mn[o][3] - mx[o][3];
            *reinterpret_cast<float4*>(out + (size_t)(r0 + o) * WO + j0) = oo;
        }
    }
}

extern "C" void kernel_launch(void* const* d_in, const int* in_sizes, int n_in,
                              void* d_out, int out_size, void* d_ws, size_t ws_size,
                              hipStream_t stream) {
    const float* x  = (const float*)d_in[0];
    const float* kh = (const float*)d_in[1];
    const float* km = (const float*)d_in[2];
    float* out = (float*)d_out;

    dim3 block(256, 1, 1);
    dim3 grid((CG + 255) / 256, HO / RPT, 1);  // 4 x 1023 = 4092 blocks ~= 2 x 2048 resident
    hipLaunchKernelGGL(hitmiss_kernel, grid, block, 0, stream, x, kh, km, out);
}

// Round 5
// 133.823 us; speedup vs baseline: 1.8727x; 1.8727x over previous
//
#include <hip/hip_runtime.h>
#include <math.h>

// Hit-miss transform: out[i][j] = min_{di,dj}(x[i+di][j+dj] - Khit[di][dj])
//                               - max_{di,dj}(x[i+di][j+dj] - Kmiss[di][dj])
// H=W=4096 fp32 input, 5x5 kernels, output 4092x4092 fp32.
//
// R8: width-8 strips on the proven scalar engine. R6/R7 showed packed-fp32
// busy-time wins exist (30->20us) but both delivery vehicles (inline asm pk,
// ext-vector pk) broke codegen (schedule destruction / scratch spill:
// R7 WRITE=425MB = 66 output + 360 scratch). Reverting to the R4/R5 scalar
// form (41.4us, VALU 73%, ~142 instr/px vs ~78 core) and attacking the
// ~64/px overhead instead: it is per-strip-fixed (row loads + addressing),
// so width 4->8 halves it per pixel (loads/px 2.5->1.9 even if the compiler
// fissions per-output-row again; core sub/min count per pixel unchanged).
// Geometry: 512 column groups = 2 x 256 exact (no guard idle), grid =
// 2 x 1023 = 2046 blocks -> packs as one ~2048-resident round (8 blk/CU)
// or two 99.9% rounds (4 blk/CU) - robust to VGPR outcome. Last group
// overlaps 4 columns (j0 = min(8cg, 4084)); duplicated columns compute
// bit-identical values (benign double-store). All-scalar fp32, same IEEE
// ops -> absmax 0.0. No launch-bounds cap, no vector types.

constexpr int KS  = 5;
constexpr int WW  = 4096;
constexpr int HO  = 4092;
constexpr int WO  = 4092;
constexpr int WPT = 8;          // output pixels per thread (strip width)
constexpr int CG  = 512;        // column groups (last overlaps by 4)
constexpr int RPT = 4;          // output rows per thread (4092 = 4*1023)

__device__ __forceinline__ float min3f(float a, float b, float c) {
    float d;
    asm("v_min3_f32 %0, %1, %2, %3" : "=v"(d) : "v"(a), "v"(b), "v"(c));
    return d;
}
__device__ __forceinline__ float max3f(float a, float b, float c) {
    float d;
    asm("v_max3_f32 %0, %1, %2, %3" : "=v"(d) : "v"(a), "v"(b), "v"(c));
    return d;
}

// 5-leaf tap-row reductions (scalar, proven form).
__device__ __forceinline__ float red5_min(float t0, float t1, float t2, float t3, float t4) {
    return min3f(min3f(t0, t1, t2), t3, t4);
}
__device__ __forceinline__ float red5_max(float t0, float t1, float t2, float t3, float t4) {
    return max3f(max3f(t0, t1, t2), t3, t4);
}
__device__ __forceinline__ float red5acc_min(float acc, float t0, float t1, float t2, float t3, float t4) {
    return fminf(min3f(t0, t1, t2), min3f(t3, t4, acc));
}
__device__ __forceinline__ float red5acc_max(float acc, float t0, float t1, float t2, float t3, float t4) {
    return fmaxf(max3f(t0, t1, t2), max3f(t3, t4, acc));
}

__global__ __launch_bounds__(256) void hitmiss_kernel(
    const float* __restrict__ x,
    const float* __restrict__ kh,
    const float* __restrict__ km,
    float* __restrict__ out)
{
    const int cg = blockIdx.x * blockDim.x + threadIdx.x;   // 0..511 exact
    const int j0 = min(cg * WPT, WO - WPT);                 // last group: 4084
    const int r0 = blockIdx.y * RPT;

    // Kernel weights: uniform addresses -> scalar (SGPR) loads.
    float wh[KS * KS], wm[KS * KS];
#pragma unroll
    for (int k = 0; k < KS * KS; ++k) {
        wh[k] = kh[k];
        wm[k] = km[k];
    }

    const float* base = x + (size_t)r0 * WW + j0;

    // Accumulators for RPT output rows x WPT pixels.
    float mn[RPT][WPT], mx[RPT][WPT];

#pragma unroll
    for (int i = 0; i < RPT + 4; ++i) {
        // Input row r0+i, elements j0..j0+11 (three 16B-aligned dwordx4).
        const float* rp = base + (size_t)i * WW;
        float4 a = *reinterpret_cast<const float4*>(rp);
        float4 b = *reinterpret_cast<const float4*>(rp + 4);
        float4 c = *reinterpret_cast<const float4*>(rp + 8);
        const float v[12] = {a.x, a.y, a.z, a.w,
                             b.x, b.y, b.z, b.w,
                             c.x, c.y, c.z, c.w};

#pragma unroll
        for (int o = 0; o < RPT; ++o) {
            const int di = i - o;              // static after unroll
            if (di < 0 || di > KS - 1) continue;
            const int kb = di * KS;
            const float h0 = wh[kb + 0], h1 = wh[kb + 1], h2 = wh[kb + 2],
                        h3 = wh[kb + 3], h4 = wh[kb + 4];
            const float m0 = wm[kb + 0], m1 = wm[kb + 1], m2 = wm[kb + 2],
                        m3 = wm[kb + 3], m4 = wm[kb + 4];

#pragma unroll
            for (int p = 0; p < WPT; ++p) {
                const float t0 = v[p + 0] - h0;
                const float t1 = v[p + 1] - h1;
                const float t2 = v[p + 2] - h2;
                const float t3 = v[p + 3] - h3;
                const float t4 = v[p + 4] - h4;
                const float u0 = v[p + 0] - m0;
                const float u1 = v[p + 1] - m1;
                const float u2 = v[p + 2] - m2;
                const float u3 = v[p + 3] - m3;
                const float u4 = v[p + 4] - m4;
                if (di == 0) {
                    mn[o][p] = red5_min(t0, t1, t2, t3, t4);
                    mx[o][p] = red5_max(u0, u1, u2, u3, u4);
                } else {
                    mn[o][p] = red5acc_min(mn[o][p], t0, t1, t2, t3, t4);
                    mx[o][p] = red5acc_max(mx[o][p], u0, u1, u2, u3, u4);
                }
            }
        }

        // Output row o = i-4 complete; store (two aligned float4) and free.
        if (i >= KS - 1) {
            const int o = i - (KS - 1);
            float* op = out + (size_t)(r0 + o) * WO + j0;
            float4 lo, hi;
            lo.x = mn[o][0] - mx[o][0];
            lo.y = mn[o][1] - mx[o][1];
            lo.z = mn[o][2] - mx[o][2];
            lo.w = mn[o][3] - mx[o][3];
            hi.x = mn[o][4] - mx[o][4];
            hi.y = mn[o][5] - mx[o][5];
            hi.z = mn[o][6] - mx[o][6];
            hi.w = mn[o][7] - mx[o][7];
            *reinterpret_cast<float4*>(op)     = lo;
            *reinterpret_cast<float4*>(op + 4) = hi;
        }
    }
}

extern "C" void kernel_launch(void* const* d_in, const int* in_sizes, int n_in,
                              void* d_out, int out_size, void* d_ws, size_t ws_size,
                              hipStream_t stream) {
    const float* x  = (const float*)d_in[0];
    const float* kh = (const float*)d_in[1];
    const float* km = (const float*)d_in[2];
    float* out = (float*)d_out;

    dim3 block(256, 1, 1);
    dim3 grid(CG / 256, HO / RPT, 1);   // 2 x 1023 = 2046 blocks
    hipLaunchKernelGGL(hitmiss_kernel, grid, block, 0, stream, x, kh, km, out);
}